// Round 8
// baseline (229.754 us; speedup 1.0000x reference)
//
#include <hip/hip_runtime.h>
#include <math.h>

#define T_DIM 5
#define Z_DIM 32
#define Y_DIM 512
#define X_DIM 512
#define N_RAYS 10000
#define N_STEPS 768
#define VOXEL_F 0.2f
#define WAVES_PER_BLOCK 8                       // 512 thr
#define RAYS_PER_BLOCK (2 * WAVES_PER_BLOCK)    // 16 (2 rays per wave)
#define N_BLOCKS (N_RAYS / RAYS_PER_BLOCK)      // 625, exact

// ws layout: float4 partials[N_BLOCKS] (10 KB) at offset 0.

struct RayP { float ox, oy, oz, ux, uy, uz, gt; int iters; };

// Per-ray params; origin passed as 15 preloaded scalars selected by ti
// (scalar selects after readfirstlane -- keeps dependent-load chain 2 deep).
__device__ inline RayP make_ray(int ray,
                                const float* __restrict__ points,
                                const int*   __restrict__ tindex,
                                const float o[15], int* ti_out)
{
    const int ti = __builtin_amdgcn_readfirstlane(tindex[ray]);
    *ti_out = ti;
    float oxm = o[0], oym = o[1], ozm = o[2];
    if (ti == 1) { oxm = o[3];  oym = o[4];  ozm = o[5];  }
    if (ti == 2) { oxm = o[6];  oym = o[7];  ozm = o[8];  }
    if (ti == 3) { oxm = o[9];  oym = o[10]; ozm = o[11]; }
    if (ti == 4) { oxm = o[12]; oym = o[13]; ozm = o[14]; }
    RayP r;
    r.ox = (oxm + 51.2f) * 5.0f;
    r.oy = (oym + 51.2f) * 5.0f;
    r.oz = (ozm + 3.2f) * 5.0f;
    const float px = (points[ray * 3 + 0] + 51.2f) * 5.0f;
    const float py = (points[ray * 3 + 1] + 51.2f) * 5.0f;
    const float pz = (points[ray * 3 + 2] + 3.2f) * 5.0f;
    const float dx = px - r.ox, dy = py - r.oy, dz = pz - r.oz;
    r.gt = sqrtf(dx * dx + dy * dy + dz * dz);
    const float inv = 1.0f / fmaxf(r.gt, 1e-6f);
    r.ux = dx * inv; r.uy = dy * inv; r.uz = dz * inv;
    // Loop bound only (per-step inb check is the exact guard; box is convex
    // so steps past exit contribute exactly 0). Origin is inside the box.
    float thi = 1e30f;
    thi = fminf(thi, fmaxf((0.0f - r.ox) / r.ux, ((float)X_DIM - r.ox) / r.ux));
    thi = fminf(thi, fmaxf((0.0f - r.oy) / r.uy, ((float)Y_DIM - r.oy) / r.uy));
    thi = fminf(thi, fmaxf((0.0f - r.oz) / r.uz, ((float)Z_DIM - r.oz) / r.uz));
    int n_active = (int)ceilf(fminf(thi, 769.0f) - 0.5f);
    n_active = min(N_STEPS, max(1, n_active));
    r.iters = (n_active + 63) >> 6;
    return r;
}

__device__ inline float ray_tau(const RayP& r, const float* __restrict__ gbase,
                                int step)
{
    const float tt = (float)step + 0.5f;
    const int ix = (int)floorf(fmaf(r.ux, tt, r.ox));
    const int iy = (int)floorf(fmaf(r.uy, tt, r.oy));
    const int iz = (int)floorf(fmaf(r.uz, tt, r.oz));
    const bool inb = (ix >= 0) & (ix < X_DIM) & (iy >= 0) & (iy < Y_DIM) &
                     (iz >= 0) & (iz < Z_DIM);
    float tau = 0.0f;
    if (inb) {
        tau = fmaxf(gbase[((size_t)iz * Y_DIM + (size_t)iy) * X_DIM + (size_t)ix], 0.0f);
    }
    return tau;
}

// TWO rays per wave: 5000 waves total -> all co-resident (no 2nd occupancy
// round; 10000 waves needed 1.22 rounds) and two independent param->gather
// chains per wave (2x memory-level parallelism). Every in-bounds 64-step
// chunk has sum(tau) ~ 25, so both rays a.s. terminate after chunk 0
// (early-out at trans < 1e-7: residual weight < 1.5e-4 m << 4.28 threshold).
// Loss path non-atomic (contended atomics cost ~70-90 us: R4 vs R5).
__global__ __launch_bounds__(512) void render_rays_kernel(
    const float* __restrict__ grid,     // [T,Z,Y,X] raw feats (relu here)
    const float* __restrict__ origin,   // [T,3] meters
    const float* __restrict__ points,   // [N_RAYS,3] meters
    const int*   __restrict__ tindex,   // [N_RAYS]
    float4*      __restrict__ partials) // [N_BLOCKS]
{
    const int wv   = (int)(threadIdx.x >> 6);                 // 0..7
    const int lane = (int)(threadIdx.x & 63);
    const int wid  = (int)blockIdx.x * WAVES_PER_BLOCK + wv;  // < 5000
    const int rayA = 2 * wid;
    const int rayB = 2 * wid + 1;

    float o[15];
#pragma unroll
    for (int k = 0; k < 15; ++k) o[k] = origin[k];

    int tiA, tiB;
    const RayP A = make_ray(rayA, points, tindex, o, &tiA);
    const RayP B = make_ray(rayB, points, tindex, o, &tiB);
    const float* gbaseA = grid + (size_t)tiA * (size_t)(Z_DIM * Y_DIM * X_DIM);
    const float* gbaseB = grid + (size_t)tiB * (size_t)(Z_DIM * Y_DIM * X_DIM);

    float accA = 0.0f, accB = 0.0f;     // per-lane weighted-t contributions
    float ecA  = 1.0f, ecB  = 1.0f;     // carry transmittance, wave-uniform
    bool aliveA = true, aliveB = true;
    const int iters = max(A.iters, B.iters);

    for (int j = 0; j < iters && (aliveA || aliveB); ++j) {
        const int step = (j << 6) + lane;
        // Issue both gathers before consuming either (independent chains).
        const float tauA = (aliveA && j < A.iters) ? ray_tau(A, gbaseA, step) : 0.0f;
        const float tauB = (aliveB && j < B.iters) ? ray_tau(B, gbaseB, step) : 0.0f;

        float sA = tauA, sB = tauB;     // inclusive lane prefix sums
#pragma unroll
        for (int d = 1; d < 64; d <<= 1) {
            const float uA = __shfl_up(sA, d, 64);
            const float uB = __shfl_up(sB, d, 64);
            if (lane >= d) { sA += uA; sB += uB; }
        }
        const float tt = (float)step + 0.5f;
        const float eA = expf(-sA);
        const float eB = expf(-sB);
        // weight = e^{-(s-tau)} - e^{-s}; exactly 0 when tau==0.
        accA += ecA * (expf(tauA - sA) - eA) * tt;
        accB += ecB * (expf(tauB - sB) - eB) * tt;
        ecA *= __shfl(eA, 63, 64);
        ecB *= __shfl(eB, 63, 64);
        aliveA = aliveA && (ecA >= 1e-7f) && (j + 1 < A.iters);
        aliveB = aliveB && (ecB >= 1e-7f) && (j + 1 < B.iters);
    }

#pragma unroll
    for (int d = 32; d >= 1; d >>= 1) {
        accA += __shfl_xor(accA, d, 64);
        accB += __shfl_xor(accB, d, 64);
    }

    // Per-block reduction of the 16 per-ray loss tuples.
    __shared__ float4 slots[RAYS_PER_BLOCK];
    if (lane == 0) {
        {
            const float pred = accA * VOXEL_F, gt = A.gt * VOXEL_F;
            const float diff = gt - pred, ad = fabsf(diff);
            float4 v; v.x = ad; v.y = 0.5f * diff * diff;
            v.z = ad / fmaxf(gt, 1e-6f); v.w = 0.0f;
            slots[2 * wv] = v;
        }
        {
            const float pred = accB * VOXEL_F, gt = B.gt * VOXEL_F;
            const float diff = gt - pred, ad = fabsf(diff);
            float4 v; v.x = ad; v.y = 0.5f * diff * diff;
            v.z = ad / fmaxf(gt, 1e-6f); v.w = 0.0f;
            slots[2 * wv + 1] = v;
        }
    }
    __syncthreads();
    if (wv == 0) {
        float a = 0.0f, b = 0.0f, c = 0.0f;
        if (lane < RAYS_PER_BLOCK) {
            const float4 v = slots[lane];
            a = v.x; b = v.y; c = v.z;
        }
#pragma unroll
        for (int d = 8; d >= 1; d >>= 1) {
            a += __shfl_xor(a, d, 64);
            b += __shfl_xor(b, d, 64);
            c += __shfl_xor(c, d, 64);
        }
        if (lane == 0) {
            float4 p; p.x = a; p.y = b; p.z = c; p.w = 0.0f;
            partials[blockIdx.x] = p;
        }
    }
}

__global__ __launch_bounds__(256) void finalize_kernel(
    const float4* __restrict__ partials, float* __restrict__ out)
{
    const int tid  = (int)threadIdx.x;
    const int lane = tid & 63;
    const int wv   = tid >> 6;
    float a = 0.0f, b = 0.0f, c = 0.0f;
    for (int i = tid; i < N_BLOCKS; i += 256) {
        const float4 v = partials[i];
        a += v.x; b += v.y; c += v.z;
    }
#pragma unroll
    for (int d = 32; d >= 1; d >>= 1) {
        a += __shfl_xor(a, d, 64);
        b += __shfl_xor(b, d, 64);
        c += __shfl_xor(c, d, 64);
    }
    __shared__ float red[4][3];
    if (lane == 0) { red[wv][0] = a; red[wv][1] = b; red[wv][2] = c; }
    __syncthreads();
    if (wv == 0 && lane < 4) {
        a = red[lane][0]; b = red[lane][1]; c = red[lane][2];
#pragma unroll
        for (int d = 2; d >= 1; d >>= 1) {
            a += __shfl_xor(a, d, 64);
            b += __shfl_xor(b, d, 64);
            c += __shfl_xor(c, d, 64);
        }
        if (lane == 0) {
            const float cnt = (float)N_RAYS;   // gt = norm >= 0 always
            out[0] = a / cnt;
            out[1] = b / cnt;
            out[2] = c / cnt;
        }
    }
}

extern "C" void kernel_launch(void* const* d_in, const int* in_sizes, int n_in,
                              void* d_out, int out_size, void* d_ws, size_t ws_size,
                              hipStream_t stream) {
    const float* grid    = (const float*)d_in[0];   // (1,5,32,512,512) fp32
    const float* origin  = (const float*)d_in[1];   // (1,5,3) fp32
    const float* points  = (const float*)d_in[2];   // (1,10000,3) fp32
    const int*   tindex  = (const int*)d_in[3];     // (1,10000) int32
    float*  out      = (float*)d_out;
    float4* partials = (float4*)d_ws;

    render_rays_kernel<<<N_BLOCKS, 512, 0, stream>>>(grid, origin, points, tindex, partials);
    finalize_kernel<<<1, 256, 0, stream>>>(partials, out);
}

// Round 9
// 205.803 us; speedup vs baseline: 1.1164x; 1.1164x over previous
//
#include <hip/hip_runtime.h>
#include <math.h>

#define T_DIM 5
#define Z_DIM 32
#define Y_DIM 512
#define X_DIM 512
#define N_RAYS 10000
#define N_STEPS 768
#define VOXEL_F 0.2f
#define RAYS_PER_BLOCK 16                      // 1024 thr = 16 waves = 16 rays
#define N_BLOCKS (N_RAYS / RAYS_PER_BLOCK)     // 625, exact

// ws layout: float4 partials[N_BLOCKS] (10 KB) at offset 0.

// R7 configuration (measured best: 206.1 us total, render ~16 us).
// One wave per ray; 16 rays per 1024-thread block, block-reduced to one
// float4 partial. Lane L of iteration j handles step 64j+L. Every in-bounds
// 64-step chunk has sum(tau) ~ 25 (tau = relu(N(0,1))), so transmittance
// dies in chunk 1 and the early-out (trans < 1e-7, residual weight
// < 1e-7*768*0.2 m = 1.5e-4 m << 4.28 threshold) fires after one iteration.
// Measured-out alternatives: tindex sorting (R3/R5: neutral-to-worse; active
// set ~8 MB is cache-resident), contended loss atomics (R4: +70-90 us),
// 2-rays-per-wave ILP fusion (R8: +24 us, register/divergence cost).
__global__ __launch_bounds__(1024) void render_rays_kernel(
    const float* __restrict__ grid,     // [T,Z,Y,X] raw feats (relu here)
    const float* __restrict__ origin,   // [T,3] meters
    const float* __restrict__ points,   // [N_RAYS,3] meters
    const int*   __restrict__ tindex,   // [N_RAYS]
    float4*      __restrict__ partials) // [N_BLOCKS]
{
    const int wv   = (int)(threadIdx.x >> 6);            // 0..15
    const int lane = (int)(threadIdx.x & 63);
    const int ray  = (int)blockIdx.x * RAYS_PER_BLOCK + wv;   // < N_RAYS always

    // Independent loads, all issued up front.
    const int ti = __builtin_amdgcn_readfirstlane(tindex[ray]);
    const float px = (points[ray * 3 + 0] + 51.2f) * 5.0f;
    const float py = (points[ray * 3 + 1] + 51.2f) * 5.0f;
    const float pz = (points[ray * 3 + 2] + 3.2f) * 5.0f;
    const float o0  = origin[0],  o1  = origin[1],  o2  = origin[2];
    const float o3  = origin[3],  o4  = origin[4],  o5  = origin[5];
    const float o6  = origin[6],  o7  = origin[7],  o8  = origin[8];
    const float o9  = origin[9],  o10 = origin[10], o11 = origin[11];
    const float o12 = origin[12], o13 = origin[13], o14 = origin[14];

    float oxm = o0, oym = o1, ozm = o2;          // ti-selected origin (scalar selects)
    if (ti == 1) { oxm = o3;  oym = o4;  ozm = o5;  }
    if (ti == 2) { oxm = o6;  oym = o7;  ozm = o8;  }
    if (ti == 3) { oxm = o9;  oym = o10; ozm = o11; }
    if (ti == 4) { oxm = o12; oym = o13; ozm = o14; }
    const float ox = (oxm + 51.2f) * 5.0f;
    const float oy = (oym + 51.2f) * 5.0f;
    const float oz = (ozm + 3.2f) * 5.0f;

    const float dx = px - ox, dy = py - oy, dz = pz - oz;
    const float gt_vox = sqrtf(dx * dx + dy * dy + dz * dz);
    const float inv = 1.0f / fmaxf(gt_vox, 1e-6f);
    const float ux = dx * inv, uy = dy * inv, uz = dz * inv;

    const float* gbase = grid + (size_t)ti * (size_t)(Z_DIM * Y_DIM * X_DIM);

    // Loop bound only (correctness rests on the per-step inb check; the box
    // is convex so steps past exit contribute exactly 0). Origin is inside.
    float thi = 1e30f;
    thi = fminf(thi, fmaxf((0.0f - ox) / ux, ((float)X_DIM - ox) / ux));
    thi = fminf(thi, fmaxf((0.0f - oy) / uy, ((float)Y_DIM - oy) / uy));
    thi = fminf(thi, fmaxf((0.0f - oz) / uz, ((float)Z_DIM - oz) / uz));
    int n_active = (int)ceilf(fminf(thi, 769.0f) - 0.5f);
    n_active = min(N_STEPS, max(1, n_active));
    const int iters = (n_active + 63) >> 6;

    float lane_acc = 0.0f;   // this lane's weighted-t contributions
    float ecarry   = 1.0f;   // exp(-sum tau of previous chunks), wave-uniform

    for (int j = 0; j < iters; ++j) {
        const int step = (j << 6) + lane;
        const float tt = (float)step + 0.5f;
        const int ix = (int)floorf(fmaf(ux, tt, ox));
        const int iy = (int)floorf(fmaf(uy, tt, oy));
        const int iz = (int)floorf(fmaf(uz, tt, oz));
        const bool inb = (ix >= 0) & (ix < X_DIM) & (iy >= 0) & (iy < Y_DIM) &
                         (iz >= 0) & (iz < Z_DIM);
        float tau = 0.0f;
        if (inb) {
            tau = fmaxf(gbase[((size_t)iz * Y_DIM + (size_t)iy) * X_DIM + (size_t)ix], 0.0f);
        }

        // Inclusive prefix sum of tau across lanes (steps are lane-ordered).
        float scan = tau;
#pragma unroll
        for (int d = 1; d < 64; d <<= 1) {
            const float up = __shfl_up(scan, d, 64);
            if (lane >= d) scan += up;
        }

        // weight = e^{-(scan-tau)} - e^{-scan}; exactly 0 when tau==0.
        const float e_scan = expf(-scan);
        lane_acc += ecarry * (expf(tau - scan) - e_scan) * tt;

        ecarry *= __shfl(e_scan, 63, 64);   // e^{-chunk total}, wave-uniform
        if (ecarry < 1e-7f) break;
    }

#pragma unroll
    for (int d = 32; d >= 1; d >>= 1) lane_acc += __shfl_xor(lane_acc, d, 64);

    // Per-block reduction of the 16 per-ray loss tuples.
    __shared__ float4 slots[RAYS_PER_BLOCK];
    if (lane == 0) {
        const float pred_m = lane_acc * VOXEL_F;
        const float gt_m   = gt_vox * VOXEL_F;
        const float diff = gt_m - pred_m;
        const float ad   = fabsf(diff);
        float4 v;
        v.x = ad;
        v.y = 0.5f * diff * diff;
        v.z = ad / fmaxf(gt_m, 1e-6f);
        v.w = 0.0f;
        slots[wv] = v;
    }
    __syncthreads();
    if (wv == 0) {
        float a = 0.0f, b = 0.0f, c = 0.0f;
        if (lane < RAYS_PER_BLOCK) {
            const float4 v = slots[lane];
            a = v.x; b = v.y; c = v.z;
        }
#pragma unroll
        for (int d = 8; d >= 1; d >>= 1) {
            a += __shfl_xor(a, d, 64);
            b += __shfl_xor(b, d, 64);
            c += __shfl_xor(c, d, 64);
        }
        if (lane == 0) {
            float4 p; p.x = a; p.y = b; p.z = c; p.w = 0.0f;
            partials[blockIdx.x] = p;
        }
    }
}

__global__ __launch_bounds__(256) void finalize_kernel(
    const float4* __restrict__ partials, float* __restrict__ out)
{
    const int tid  = (int)threadIdx.x;
    const int lane = tid & 63;
    const int wv   = tid >> 6;
    float a = 0.0f, b = 0.0f, c = 0.0f;
    for (int i = tid; i < N_BLOCKS; i += 256) {
        const float4 v = partials[i];
        a += v.x; b += v.y; c += v.z;
    }
#pragma unroll
    for (int d = 32; d >= 1; d >>= 1) {
        a += __shfl_xor(a, d, 64);
        b += __shfl_xor(b, d, 64);
        c += __shfl_xor(c, d, 64);
    }
    __shared__ float red[4][3];
    if (lane == 0) { red[wv][0] = a; red[wv][1] = b; red[wv][2] = c; }
    __syncthreads();
    if (wv == 0 && lane < 4) {
        a = red[lane][0]; b = red[lane][1]; c = red[lane][2];
#pragma unroll
        for (int d = 2; d >= 1; d >>= 1) {
            a += __shfl_xor(a, d, 64);
            b += __shfl_xor(b, d, 64);
            c += __shfl_xor(c, d, 64);
        }
        if (lane == 0) {
            const float cnt = (float)N_RAYS;   // gt = norm >= 0 always
            out[0] = a / cnt;
            out[1] = b / cnt;
            out[2] = c / cnt;
        }
    }
}

extern "C" void kernel_launch(void* const* d_in, const int* in_sizes, int n_in,
                              void* d_out, int out_size, void* d_ws, size_t ws_size,
                              hipStream_t stream) {
    const float* grid    = (const float*)d_in[0];   // (1,5,32,512,512) fp32
    const float* origin  = (const float*)d_in[1];   // (1,5,3) fp32
    const float* points  = (const float*)d_in[2];   // (1,10000,3) fp32
    const int*   tindex  = (const int*)d_in[3];     // (1,10000) int32
    float*  out      = (float*)d_out;
    float4* partials = (float4*)d_ws;

    render_rays_kernel<<<N_BLOCKS, 1024, 0, stream>>>(grid, origin, points, tindex, partials);
    finalize_kernel<<<1, 256, 0, stream>>>(partials, out);
}